// Round 3
// baseline (1073.537 us; speedup 1.0000x reference)
//
#include <hip/hip_runtime.h>
#include <math.h>

#define NE 64            // experts
#define TPB 64           // tokens per block (kernel 1)
#define HDIM 4096
#define SEQ 4096
#define NTOK 32768       // B*S
#define CAP 128          // expert capacity
#define LSW 88           // LDS w-tile row stride in bf16 (176B: 16B-aligned, conflict-free b128)
#define LSF 68           // logits row stride in floats
#define AMB_TH 2.0e-3f   // ambiguity threshold on fp32 logit gaps (split-bf16 err <= ~3e-4 worst)

typedef __attribute__((ext_vector_type(8))) short bf16x8;
typedef __attribute__((ext_vector_type(4))) float f32x4;
typedef __attribute__((ext_vector_type(4))) unsigned short us4;

__device__ __forceinline__ unsigned short bf16_rtne(float f) {
    unsigned u = __float_as_uint(f);
    return (unsigned short)((u + 0x7FFFu + ((u >> 16) & 1u)) >> 16);
}
__device__ __forceinline__ void split2(float f, unsigned short& hi, unsigned short& lo) {
    unsigned u = __float_as_uint(f);
    unsigned r = (u + 0x7FFFu + ((u >> 16) & 1u)) & 0xFFFF0000u;
    hi = (unsigned short)(r >> 16);
    lo = bf16_rtne(f - __uint_as_float(r));  // exact residual, then RTNE
}

// ---------------------------------------------------------------------------
// Kernel 0: split router weights into bf16 hi/lo planes (1 MB total, once)
// ---------------------------------------------------------------------------
__global__ __launch_bounds__(256) void k_prep(
    const float* __restrict__ rw,
    unsigned short* __restrict__ wh, unsigned short* __restrict__ wl)
{
    const size_t base = (size_t)blockIdx.x * HDIM + threadIdx.x * 16;
#pragma unroll
    for (int i = 0; i < 4; ++i) {
        const f32x4 v = *(const f32x4*)(rw + base + i * 4);
        us4 h4, l4;
#pragma unroll
        for (int j = 0; j < 4; ++j) {
            unsigned short hh, ll;
            split2(v[j], hh, ll);
            h4[j] = hh;
            l4[j] = ll;
        }
        *(us4*)(wh + base + i * 4) = h4;
        *(us4*)(wl + base + i * 4) = l4;
    }
}

// ---------------------------------------------------------------------------
// Kernel 1: logits GEMM via split-bf16 MFMA (hh*wh + hh*wl + hl*wh, fp32 acc)
//           + softmax + top3 + loss partials + zero dispatch/combine
//           + in-block fp64 fixup of ambiguous tokens.
// grid = 512 blocks (64 tokens x 64 experts each), 256 threads = 4 waves.
// Wave w owns tokens 16w..16w+15 (a-frags straight from global, no LDS for h).
// ---------------------------------------------------------------------------
__global__ __launch_bounds__(256) void k_router(
    const float* __restrict__ hs,
    const unsigned short* __restrict__ wh, const unsigned short* __restrict__ wl,
    const float* __restrict__ rw,
    float* __restrict__ dispatch, float* __restrict__ combine,
    float* __restrict__ probs_out,
    int* __restrict__ idx_buf, float* __restrict__ wgt_buf,
    float* __restrict__ partials)
{
    __shared__ short sw[2][2][64 * LSW];   // [dbuf][part][expert*LSW + k] bf16
    __shared__ double dpart[NE][4];
    __shared__ float red1[4], red2[4];
    __shared__ int nflag, flist[64];

    const int tid  = threadIdx.x;
    const int wv   = tid >> 6;          // wave 0..3
    const int lane = tid & 63;
    const int lr   = lane & 15;         // fragment row (M or N within 16-tile)
    const int kg   = lane >> 4;         // fragment k-group 0..3
    const int tokBase = blockIdx.x * TPB;

    if (tid == 0) nflag = 0;

    f32x4 acc[4];
#pragma unroll
    for (int t = 0; t < 4; ++t) acc[t] = (f32x4){0.f, 0.f, 0.f, 0.f};

    // h: this lane's token row (fragment A loaded direct from global)
    const float* hrow = hs + (size_t)(tokBase + wv * 16 + lr) * HDIM + kg * 8;

    // w staging: thread (expert we, quarter wq) moves 64B per chunk
    const int we = tid & 63;
    const int wq = tid >> 6;            // 0..3
    const int wp = wq >> 1;             // part: 0=hi, 1=lo
    const int wk = (wq & 1) * 32;       // k offset (bf16)
    const unsigned short* wsrc = (wp ? wl : wh) + (size_t)we * HDIM + wk;
    short* wdst0 = &sw[0][wp][we * LSW + wk];
    short* wdst1 = &sw[1][wp][we * LSW + wk];

    f32x4 hrA[4], hrB[4];
    bf16x8 wrA[4], wrB[4];

    // ---- prologue: chunk0 -> buf0, prefetch chunk1 into regs ----
#pragma unroll
    for (int i = 0; i < 4; ++i) wrA[i] = *(const bf16x8*)(wsrc + i * 8);
#pragma unroll
    for (int s = 0; s < 2; ++s)
#pragma unroll
        for (int h2 = 0; h2 < 2; ++h2)
            hrA[s * 2 + h2] = *(const f32x4*)(hrow + s * 32 + h2 * 4);
#pragma unroll
    for (int i = 0; i < 4; ++i) *(bf16x8*)(wdst0 + i * 8) = wrA[i];
#pragma unroll
    for (int i = 0; i < 4; ++i) wrB[i] = *(const bf16x8*)(wsrc + 64 + i * 8);
#pragma unroll
    for (int s = 0; s < 2; ++s)
#pragma unroll
        for (int h2 = 0; h2 < 2; ++h2)
            hrB[s * 2 + h2] = *(const f32x4*)(hrow + 64 + s * 32 + h2 * 4);
    __syncthreads();

#define CONVERT_A(HR, AH, AL)                                              \
    {                                                                      \
        _Pragma("unroll")                                                  \
        for (int s = 0; s < 2; ++s) {                                      \
            _Pragma("unroll")                                              \
            for (int j = 0; j < 8; ++j) {                                  \
                unsigned short hi_, lo_;                                   \
                split2(HR[s * 2 + (j >> 2)][j & 3], hi_, lo_);             \
                AH[s][j] = (short)hi_;                                     \
                AL[s][j] = (short)lo_;                                     \
            }                                                              \
        }                                                                  \
    }

#define MFMA_PHASE(BUF, AH, AL)                                            \
    {                                                                      \
        _Pragma("unroll")                                                  \
        for (int s = 0; s < 2; ++s) {                                      \
            _Pragma("unroll")                                              \
            for (int t = 0; t < 4; ++t) {                                  \
                const bf16x8 bh = *(const bf16x8*)&sw[BUF][0][(t * 16 + lr) * LSW + s * 32 + kg * 8]; \
                const bf16x8 bl = *(const bf16x8*)&sw[BUF][1][(t * 16 + lr) * LSW + s * 32 + kg * 8]; \
                acc[t] = __builtin_amdgcn_mfma_f32_16x16x32_bf16(AH[s], bh, acc[t], 0, 0, 0); \
                acc[t] = __builtin_amdgcn_mfma_f32_16x16x32_bf16(AH[s], bl, acc[t], 0, 0, 0); \
                acc[t] = __builtin_amdgcn_mfma_f32_16x16x32_bf16(AL[s], bh, acc[t], 0, 0, 0); \
            }                                                              \
        }                                                                  \
    }

    bf16x8 ahi[2], alo[2];
    for (int c = 0; c < 64; c += 2) {
        // ---- even sub-iter: chunk c. read buf0 + hrA; write wrB->buf1; load c+2 ----
        CONVERT_A(hrA, ahi, alo)
#pragma unroll
        for (int i = 0; i < 4; ++i) *(bf16x8*)(wdst1 + i * 8) = wrB[i];
        {
            const int cn = (c + 2 < 64) ? c + 2 : 63;
#pragma unroll
            for (int i = 0; i < 4; ++i) wrA[i] = *(const bf16x8*)(wsrc + cn * 64 + i * 8);
#pragma unroll
            for (int s = 0; s < 2; ++s)
#pragma unroll
                for (int h2 = 0; h2 < 2; ++h2)
                    hrA[s * 2 + h2] = *(const f32x4*)(hrow + cn * 64 + s * 32 + h2 * 4);
        }
        MFMA_PHASE(0, ahi, alo)
        __syncthreads();

        // ---- odd sub-iter: chunk c+1. read buf1 + hrB; write wrA->buf0; load c+3 ----
        CONVERT_A(hrB, ahi, alo)
#pragma unroll
        for (int i = 0; i < 4; ++i) *(bf16x8*)(wdst0 + i * 8) = wrA[i];
        {
            const int cn = (c + 3 < 64) ? c + 3 : 63;
#pragma unroll
            for (int i = 0; i < 4; ++i) wrB[i] = *(const bf16x8*)(wsrc + cn * 64 + i * 8);
#pragma unroll
            for (int s = 0; s < 2; ++s)
#pragma unroll
                for (int h2 = 0; h2 < 2; ++h2)
                    hrB[s * 2 + h2] = *(const f32x4*)(hrow + cn * 64 + s * 32 + h2 * 4);
        }
        MFMA_PHASE(1, ahi, alo)
        __syncthreads();
    }

    // ---- epilogue: acc -> logits LDS overlay (C layout: col=lane&15, row=kg*4+r)
    float* lgd = (float*)&sw[0][0][0];   // [64][LSF] floats, 17.4 KB < 44 KB
#pragma unroll
    for (int t = 0; t < 4; ++t)
#pragma unroll
        for (int r = 0; r < 4; ++r)
            lgd[(wv * 16 + kg * 4 + r) * LSF + t * 16 + lr] = acc[t][r];
    __syncthreads();

    // zero dispatch & combine for this block's tokens (d_out is poisoned)
    {
        const f32x4 z4 = (f32x4){0.f, 0.f, 0.f, 0.f};
        f32x4* dp = (f32x4*)(dispatch + (size_t)tokBase * NE);
        f32x4* cp = (f32x4*)(combine + (size_t)tokBase * NE);
#pragma unroll
        for (int m = 0; m < 4; ++m) {
            dp[m * 256 + tid] = z4;
            cp[m * 256 + tid] = z4;
        }
    }

    float p2 = 0.f, zl = 0.f;
    if (tid < TPB) {
        const float* rowl = &lgd[tid * LSF];

        // top-3 (strict > => lowest index wins ties, matching lax.top_k)
        float b0 = -3.4e38f, b1 = -3.4e38f, b2 = -3.4e38f;
        int i0 = 0, i1 = 0;
#pragma unroll
        for (int e = 0; e < NE; ++e) {
            const float l = rowl[e];
            if (l > b0)      { b2 = b1; b1 = b0; i1 = i0; b0 = l; i0 = e; }
            else if (l > b1) { b2 = b1; b1 = l; i1 = e; }
            else if (l > b2) { b2 = l; }
        }

        // softmax (mx == b0) + probs + loss partials
        float fp[NE];
        float sum = 0.f;
#pragma unroll
        for (int e = 0; e < NE; ++e) {
            const float s = expf(rowl[e] - b0);
            sum += s;
            fp[e] = s;
        }
        const float inv = 1.f / sum;
        float p2l = 0.f;
#pragma unroll
        for (int e = 0; e < NE; ++e) {
            const float p = fp[e] * inv;
            fp[e] = p;
            p2l += p * p;
        }
        f32x4* gp = (f32x4*)(probs_out + (size_t)(tokBase + tid) * NE);
#pragma unroll
        for (int q = 0; q < 16; ++q) gp[q] = *(f32x4*)&fp[4 * q];

        p2 = p2l;
        const float lse = b0 + logf(sum);
        zl = lse * lse;

        const float w0 = 1.f / (1.f + expf(b1 - b0));
        const float w1 = 1.f / (1.f + expf(b0 - b1));
        idx_buf[(size_t)(tokBase + tid) * 2 + 0] = i0;
        idx_buf[(size_t)(tokBase + tid) * 2 + 1] = i1;
        wgt_buf[(size_t)(tokBase + tid) * 2 + 0] = w0;
        wgt_buf[(size_t)(tokBase + tid) * 2 + 1] = w1;

        // flag tokens whose ranking is within split-bf16 GEMM error of a tie
        if ((b0 - b1 < AMB_TH) || (b1 - b2 < AMB_TH)) {
            const int p = atomicAdd(&nflag, 1);
            flist[p] = tid;
        }
    }

    // block-reduce loss partials (deterministic; waves 1-3 contribute zeros)
#pragma unroll
    for (int off = 32; off; off >>= 1) {
        p2 += __shfl_down(p2, off);
        zl += __shfl_down(zl, off);
    }
    if (lane == 0) { red1[wv] = p2; red2[wv] = zl; }
    __syncthreads();
    if (tid == 0) {
        partials[blockIdx.x * 2 + 0] = red1[0] + red1[1] + red1[2] + red1[3];
        partials[blockIdx.x * 2 + 1] = red2[0] + red2[1] + red2[2] + red2[3];
    }

    // ---- in-block fp64 fixup of ambiguous tokens (expected ~0.45 per block) ----
    __syncthreads();
    const int nf = nflag;
    for (int f = 0; f < nf; ++f) {
        const int t = tokBase + flist[f];
        const float* hp  = hs + (size_t)t * HDIM + wq * 1024;   // uniform per wave-quarter
        const float* wp2 = rw + (size_t)we * HDIM + wq * 1024;
        double a = 0.0;
#pragma unroll 4
        for (int i = 0; i < 256; ++i) {
            const f32x4 hv = *(const f32x4*)(hp + i * 4);
            const f32x4 wv4 = *(const f32x4*)(wp2 + i * 4);
            a = fma((double)hv[0], (double)wv4[0], a);
            a = fma((double)hv[1], (double)wv4[1], a);
            a = fma((double)hv[2], (double)wv4[2], a);
            a = fma((double)hv[3], (double)wv4[3], a);
        }
        dpart[we][wq] = a;
        __syncthreads();
        if (tid < NE)
            dpart[tid][0] = dpart[tid][0] + dpart[tid][1] + dpart[tid][2] + dpart[tid][3];
        __syncthreads();
        if (tid == 0) {
            double b0 = -1.0e300, b1 = -1.0e300;
            int i0 = 0, i1 = 0;
            for (int x = 0; x < NE; ++x) {
                const double l = dpart[x][0];
                if (l > b0)      { b1 = b0; i1 = i0; b0 = l; i0 = x; }
                else if (l > b1) { b1 = l; i1 = x; }
            }
            const double w0 = 1.0 / (1.0 + exp(b1 - b0));
            const double w1 = 1.0 / (1.0 + exp(b0 - b1));
            idx_buf[(size_t)t * 2 + 0] = i0;
            idx_buf[(size_t)t * 2 + 1] = i1;
            wgt_buf[(size_t)t * 2 + 0] = (float)w0;
            wgt_buf[(size_t)t * 2 + 1] = (float)w1;
        }
        __syncthreads();
    }
}

// ---------------------------------------------------------------------------
// Kernel 2: capacity-limited dispatch. ONE WAVE per (batch, expert) —
// no barriers, ballot-prefix scan in k-major order, early exit at capacity.
// grid = 128 blocks x 256 threads = 512 waves.
// ---------------------------------------------------------------------------
__global__ __launch_bounds__(256) void k_dispatch(
    const int* __restrict__ idx_buf, const float* __restrict__ wgt_buf,
    float* __restrict__ dispatch, float* __restrict__ combine)
{
    const int gw = (blockIdx.x << 2) | (threadIdx.x >> 6);  // 0..511
    const int e = gw & 63;
    const int b = gw >> 6;
    const int lane = threadIdx.x & 63;
    const int base = b * SEQ;

    int running = 0;
    for (int chunk = 0; chunk < 128; ++chunk) {
        const int j = (chunk << 6) | lane;   // k-major: j = k*SEQ + s
        const int k = j >> 12;
        const int s = j & (SEQ - 1);
        const int my = idx_buf[(size_t)(base + s) * 2 + k];
        const bool m = (my == e);
        const unsigned long long bal = __ballot(m);
        if (m) {
            const int pos = running + __popcll(bal & ((1ull << lane) - 1ull));
            if (pos < CAP) {
                const size_t o = (size_t)(base + s) * NE + e;
                dispatch[o] = 1.0f;
                combine[o] = wgt_buf[(size_t)(base + s) * 2 + k];
            }
        }
        running += __popcll(bal);
        if (running >= CAP) break;   // capacity full: no further stores possible
    }
}

// ---------------------------------------------------------------------------
// Kernel 3: deterministic final reduce of 512 loss partials
// ---------------------------------------------------------------------------
__global__ __launch_bounds__(256) void k_final(
    const float* __restrict__ partials, float* __restrict__ out)
{
    __shared__ float r1[4], r2[4];
    const int tid = threadIdx.x;
    float a = partials[tid * 2 + 0] + partials[(tid + 256) * 2 + 0];
    float b = partials[tid * 2 + 1] + partials[(tid + 256) * 2 + 1];
#pragma unroll
    for (int off = 32; off; off >>= 1) {
        a += __shfl_down(a, off);
        b += __shfl_down(b, off);
    }
    const int lane = tid & 63, wid = tid >> 6;
    if (lane == 0) { r1[wid] = a; r2[wid] = b; }
    __syncthreads();
    if (tid == 0) {
        float at = r1[0] + r1[1] + r1[2] + r1[3];
        float bt = r2[0] + r2[1] + r2[2] + r2[3];
        out[0] = at / (float)NTOK * (float)NE;   // aux_loss
        out[1] = bt / (float)NTOK;               // z_loss
    }
}

extern "C" void kernel_launch(void* const* d_in, const int* in_sizes, int n_in,
                              void* d_out, int out_size, void* d_ws, size_t ws_size,
                              hipStream_t stream)
{
    const float* hs = (const float*)d_in[0];   // [8,4096,4096]
    const float* rw = (const float*)d_in[1];   // [64,4096]
    float* out = (float*)d_out;
    float* dispatch = out;                     // [B,S,E] = 2097152
    float* combine  = out + 2097152;
    float* probs    = out + 2 * 2097152;
    float* scalars  = out + 3 * 2097152;       // aux, z

    int*   idx_buf  = (int*)d_ws;                                    // 256 KB
    float* wgt_buf  = (float*)((char*)d_ws + 262144);                // 256 KB
    float* partials = (float*)((char*)d_ws + 524288);                // 4 KB
    unsigned short* whbuf = (unsigned short*)((char*)d_ws + 786432); // 512 KB
    unsigned short* wlbuf = (unsigned short*)((char*)d_ws + 1310720);// 512 KB

    hipLaunchKernelGGL(k_prep, dim3(NE), dim3(256), 0, stream, rw, whbuf, wlbuf);
    hipLaunchKernelGGL(k_router, dim3(NTOK / TPB), dim3(256), 0, stream,
                       hs, whbuf, wlbuf, rw, dispatch, combine, probs,
                       idx_buf, wgt_buf, partials);
    hipLaunchKernelGGL(k_dispatch, dim3(128), dim3(256), 0, stream,
                       idx_buf, wgt_buf, dispatch, combine);
    hipLaunchKernelGGL(k_final, dim3(1), dim3(256), 0, stream,
                       partials, scalars);
}